// Round 1
// 809.367 us; speedup vs baseline: 1.2946x; 1.2946x over previous
//
#include <hip/hip_runtime.h>
#include <hip/hip_bf16.h>
#include <stdint.h>

#define T_TOK   16384
#define INF     4096
#define OUTF    4096
#define NEXP    64
#define TOPK    16
#define RDIM    16
#define BOT     512

typedef float  f32x4  __attribute__((ext_vector_type(4)));
typedef short  bf16x8 __attribute__((ext_vector_type(8)));

__device__ __forceinline__ unsigned short f2bf(float f) {
    union { float f; unsigned int u; } c; c.f = f;
    unsigned int r = c.u + 0x7fffu + ((c.u >> 16) & 1u);
    return (unsigned short)(r >> 16);
}

// async global->LDS, 16B per lane. LDS dest must be wave-uniform base + lane*16.
__device__ __forceinline__ void gld_lds16(const void* g, void* l) {
    __builtin_amdgcn_global_load_lds(
        (const __attribute__((address_space(1))) unsigned int*)(uintptr_t)g,
        (__attribute__((address_space(3))) unsigned int*)(unsigned int)(uintptr_t)l,
        16, 0, 0);
}

// ---------------- weight cast: A_w (512x4096) + B_w (4096x512) fp32 -> bf16 ----
__global__ void __launch_bounds__(256) cast_w(const float* __restrict__ A,
                                              const float* __restrict__ B,
                                              unsigned short* __restrict__ Ab,
                                              unsigned short* __restrict__ Bb) {
    int i = blockIdx.x * 256 + threadIdx.x;
    const int nA = (BOT * INF) / 4;
    const float* src; unsigned short* dst; int k;
    if (i < nA) { src = A; dst = Ab; k = i; }
    else        { src = B; dst = Bb; k = i - nA; }
    f32x4 v = ((const f32x4*)src)[k];
    ushort4 o;
    o.x = f2bf(v.x); o.y = f2bf(v.y); o.z = f2bf(v.z); o.w = f2bf(v.w);
    ((ushort4*)dst)[k] = o;
}

// ---------------- router v2: sync-free, LDS-free, wave = 4 tokens -------------
// Each lane owns d-slice {lane*4 + j*256 : j=0..15}; acc[r][t] in registers;
// one butterfly allreduce per 4-token group; fp32 throughout (selection-stable).
#define RTM 4   // tokens per wave

__global__ void __launch_bounds__(256) router_kernel(
    const float* __restrict__ x,      // [T][4096]
    const float* __restrict__ Wq,     // [16][4096]
    const float* __restrict__ keys,   // [64][16]
    unsigned short* __restrict__ xb,  // [T][4096] bf16 out
    float* __restrict__ gate)         // [T][64] out
{
    const int tid  = threadIdx.x;
    const int lane = tid & 63;
    const int wave = tid >> 6;
    const int g    = blockIdx.x * 4 + wave;       // 4096 groups
    const size_t t0 = (size_t)g * RTM;

    float acc[RDIM][RTM] = {};

    const float*   xp = x  + t0 * INF + lane * 4;
    const float*   wp = Wq + lane * 4;
    unsigned short* xo = xb + t0 * INF + lane * 4;

    #pragma unroll 2
    for (int j = 0; j < 16; ++j) {
        const int d = j * 256;
        f32x4 xv[RTM];
        #pragma unroll
        for (int t = 0; t < RTM; ++t)
            xv[t] = *(const f32x4*)(xp + (size_t)t * INF + d);
        // fused bf16 cast+store (8B/lane, coalesced)
        #pragma unroll
        for (int t = 0; t < RTM; ++t) {
            ushort4 bv;
            bv.x = f2bf(xv[t].x); bv.y = f2bf(xv[t].y);
            bv.z = f2bf(xv[t].z); bv.w = f2bf(xv[t].w);
            *(ushort4*)(xo + (size_t)t * INF + d) = bv;
        }
        // Wq rows in two halves of 8 to bound live VGPRs
        #pragma unroll
        for (int rh = 0; rh < 2; ++rh) {
            f32x4 wv[8];
            #pragma unroll
            for (int r = 0; r < 8; ++r)
                wv[r] = *(const f32x4*)(wp + (size_t)(rh * 8 + r) * INF + d);
            #pragma unroll
            for (int r = 0; r < 8; ++r) {
                #pragma unroll
                for (int t = 0; t < RTM; ++t)
                    acc[rh * 8 + r][t] += wv[r].x * xv[t].x + wv[r].y * xv[t].y
                                        + wv[r].z * xv[t].z + wv[r].w * xv[t].w;
            }
        }
    }

    // single butterfly allreduce: every lane ends with full q[r][t]
    #pragma unroll
    for (int off = 1; off < 64; off <<= 1) {
        #pragma unroll
        for (int r = 0; r < RDIM; ++r)
            #pragma unroll
            for (int t = 0; t < RTM; ++t)
                acc[r][t] += __shfl_xor(acc[r][t], off, 64);
    }

    // lane = expert; keys row in registers
    f32x4 kreg[4];
    #pragma unroll
    for (int i = 0; i < 4; ++i)
        kreg[i] = *(const f32x4*)&keys[lane * RDIM + i * 4];

    #pragma unroll
    for (int t = 0; t < RTM; ++t) {
        float s = 0.0f;
        #pragma unroll
        for (int i = 0; i < 4; ++i) {
            s += acc[i*4+0][t] * kreg[i].x + acc[i*4+1][t] * kreg[i].y
               + acc[i*4+2][t] * kreg[i].z + acc[i*4+3][t] * kreg[i].w;
        }
        // rank = #experts strictly better (value desc, index asc) == top_k tie rule
        int rank = 0;
        for (int j = 0; j < 64; ++j) {
            float sj = __shfl(s, j, 64);
            rank += (sj > s || (sj == s && j < lane)) ? 1 : 0;
        }
        float m = s;
        #pragma unroll
        for (int off = 32; off > 0; off >>= 1)
            m = fmaxf(m, __shfl_xor(m, off, 64));
        float e = (rank < TOPK) ? __expf(s - m) : 0.0f;
        float sum = e;
        #pragma unroll
        for (int off = 32; off > 0; off >>= 1)
            sum += __shfl_xor(sum, off, 64);
        gate[(t0 + t) * NEXP + lane] = e / sum;
    }
}

// ---------------- m97-style bf16 B^T GEMM: C[M,N] = A[M,K] * B[N,K]^T --------
// EPI 0: C -> bf16 Zg with per-(row,expert) gate.  EPI 1: C -> fp32 out * 2.0
template <int EPI>
__global__ void __launch_bounds__(256) gemm_bt(
    const unsigned short* __restrict__ A,
    const unsigned short* __restrict__ Bm,
    const float* __restrict__ gate,
    unsigned short* __restrict__ Cb,
    float* __restrict__ Cf,
    const int M, const int N, const int K)
{
    constexpr int BM = 128, BN = 128, BK = 32;
    __shared__ __align__(16) unsigned short As[BM * BK];   // 8 KB
    __shared__ __align__(16) unsigned short Bs[BN * BK];   // 8 KB

    const int tid  = threadIdx.x;
    const int lane = tid & 63;
    const int wave = tid >> 6;
    const int wr = wave >> 1, wc = wave & 1;
    const int bm = blockIdx.y * BM;
    const int bn = blockIdx.x * BN;

    f32x4 acc[4][4] = {};

    const int srow = tid >> 2;
    const int scol = (tid & 3) * 8;
    const unsigned short* Ap = A  + (size_t)(bm + srow) * K + scol;
    const unsigned short* Bp = Bm + (size_t)(bn + srow) * K + scol;
    unsigned short* AsP = &As[tid * 8];
    unsigned short* BsP = &Bs[tid * 8];

    const int fm = lane & 15;
    const int fk = (lane >> 4) * 8;

    for (int k0 = 0; k0 < K; k0 += BK) {
        __syncthreads();
        gld_lds16(Ap,                  AsP);
        gld_lds16(Ap + (size_t)64 * K, AsP + 64 * BK);
        gld_lds16(Bp,                  BsP);
        gld_lds16(Bp + (size_t)64 * K, BsP + 64 * BK);
        Ap += BK; Bp += BK;
        __syncthreads();

        bf16x8 af[4], bfr[4];
        #pragma unroll
        for (int i = 0; i < 4; ++i)
            af[i] = *(const bf16x8*)&As[(wr * 64 + i * 16 + fm) * BK + fk];
        #pragma unroll
        for (int j = 0; j < 4; ++j)
            bfr[j] = *(const bf16x8*)&Bs[(wc * 64 + j * 16 + fm) * BK + fk];
        #pragma unroll
        for (int i = 0; i < 4; ++i)
            #pragma unroll
            for (int j = 0; j < 4; ++j)
                acc[i][j] = __builtin_amdgcn_mfma_f32_16x16x32_bf16(af[i], bfr[j], acc[i][j], 0, 0, 0);
    }

    // epilogue: C/D layout col=lane&15, row=(lane>>4)*4+reg  (m89/m91-verified)
    const int row0 = (lane >> 4) * 4;
    const int col  = lane & 15;
    #pragma unroll
    for (int i = 0; i < 4; ++i) {
        #pragma unroll
        for (int j = 0; j < 4; ++j) {
            const int nn = bn + wc * 64 + j * 16 + col;
            #pragma unroll
            for (int r = 0; r < 4; ++r) {
                const int mm = bm + wr * 64 + i * 16 + row0 + r;
                if (EPI == 0) {
                    float g = gate[(size_t)mm * NEXP + (nn >> 3)];
                    Cb[(size_t)mm * N + nn] = f2bf(acc[i][j][r] * g);
                } else {
                    Cf[(size_t)mm * N + nn] = acc[i][j][r] * 2.0f;
                }
            }
        }
    }
}

extern "C" void kernel_launch(void* const* d_in, const int* in_sizes, int n_in,
                              void* d_out, int out_size, void* d_ws, size_t ws_size,
                              hipStream_t stream) {
    const float* x    = (const float*)d_in[0];
    const float* A_w  = (const float*)d_in[1];
    const float* B_w  = (const float*)d_in[2];
    const float* Wq   = (const float*)d_in[3];
    const float* keys = (const float*)d_in[4];
    float* out = (float*)d_out;

    char* ws = (char*)d_ws;
    unsigned short* xb = (unsigned short*)(ws);                       // 134217728 B
    unsigned short* Ab = (unsigned short*)(ws + 134217728);           //   4194304 B
    unsigned short* Bb = (unsigned short*)(ws + 138412032);           //   4194304 B
    float*        gate = (float*)        (ws + 142606336);            //   4194304 B
    unsigned short* Zg = (unsigned short*)(ws + 146800640);           //  16777216 B
    // total ws use: 163,577,856 B

    cast_w<<<dim3(4096), dim3(256), 0, stream>>>(A_w, B_w, Ab, Bb);
    // 4096 token-groups of 4, one group per wave, 4 waves per block
    router_kernel<<<dim3(T_TOK / (RTM * 4)), dim3(256), 0, stream>>>(x, Wq, keys, xb, gate);
    gemm_bt<0><<<dim3(BOT / 128, T_TOK / 128), dim3(256), 0, stream>>>(
        xb, Ab, gate, Zg, nullptr, T_TOK, BOT, INF);
    gemm_bt<1><<<dim3(OUTF / 128, T_TOK / 128), dim3(256), 0, stream>>>(
        Zg, Bb, nullptr, nullptr, out, T_TOK, OUTF, BOT);
}

// Round 2
// 722.599 us; speedup vs baseline: 1.4500x; 1.1201x over previous
//
#include <hip/hip_runtime.h>
#include <hip/hip_bf16.h>
#include <stdint.h>

#define T_TOK   16384
#define INF     4096
#define OUTF    4096
#define NEXP    64
#define TOPK    16
#define RDIM    16
#define BOT     512

typedef float  f32x4  __attribute__((ext_vector_type(4)));
typedef short  bf16x8 __attribute__((ext_vector_type(8)));

__device__ __forceinline__ unsigned short f2bf(float f) {
    union { float f; unsigned int u; } c; c.f = f;
    unsigned int r = c.u + 0x7fffu + ((c.u >> 16) & 1u);
    return (unsigned short)(r >> 16);
}

// async global->LDS, 16B per lane. LDS dest must be wave-uniform base + lane*16.
__device__ __forceinline__ void gld_lds16(const void* g, void* l) {
    __builtin_amdgcn_global_load_lds(
        (const __attribute__((address_space(1))) unsigned int*)(uintptr_t)g,
        (__attribute__((address_space(3))) unsigned int*)(unsigned int)(uintptr_t)l,
        16, 0, 0);
}

// ---------------- weight cast: A_w (512x4096) + B_w (4096x512) fp32 -> bf16 ----
__global__ void __launch_bounds__(256) cast_w(const float* __restrict__ A,
                                              const float* __restrict__ B,
                                              unsigned short* __restrict__ Ab,
                                              unsigned short* __restrict__ Bb) {
    int i = blockIdx.x * 256 + threadIdx.x;
    const int nA = (BOT * INF) / 4;
    const float* src; unsigned short* dst; int k;
    if (i < nA) { src = A; dst = Ab; k = i; }
    else        { src = B; dst = Bb; k = i - nA; }
    f32x4 v = ((const f32x4*)src)[k];
    ushort4 o;
    o.x = f2bf(v.x); o.y = f2bf(v.y); o.z = f2bf(v.z); o.w = f2bf(v.w);
    ((ushort4*)dst)[k] = o;
}

// ---------------- router v2: sync-free, LDS-free, wave = 4 tokens -------------
#define RTM 4   // tokens per wave

__global__ void __launch_bounds__(256) router_kernel(
    const float* __restrict__ x,      // [T][4096]
    const float* __restrict__ Wq,     // [16][4096]
    const float* __restrict__ keys,   // [64][16]
    unsigned short* __restrict__ xb,  // [T][4096] bf16 out
    float* __restrict__ gate)         // [T][64] out
{
    const int tid  = threadIdx.x;
    const int lane = tid & 63;
    const int wave = tid >> 6;
    const int g    = blockIdx.x * 4 + wave;       // 4096 groups
    const size_t t0 = (size_t)g * RTM;

    float acc[RDIM][RTM] = {};

    const float*   xp = x  + t0 * INF + lane * 4;
    const float*   wp = Wq + lane * 4;
    unsigned short* xo = xb + t0 * INF + lane * 4;

    #pragma unroll 2
    for (int j = 0; j < 16; ++j) {
        const int d = j * 256;
        f32x4 xv[RTM];
        #pragma unroll
        for (int t = 0; t < RTM; ++t)
            xv[t] = *(const f32x4*)(xp + (size_t)t * INF + d);
        #pragma unroll
        for (int t = 0; t < RTM; ++t) {
            ushort4 bv;
            bv.x = f2bf(xv[t].x); bv.y = f2bf(xv[t].y);
            bv.z = f2bf(xv[t].z); bv.w = f2bf(xv[t].w);
            *(ushort4*)(xo + (size_t)t * INF + d) = bv;
        }
        #pragma unroll
        for (int rh = 0; rh < 2; ++rh) {
            f32x4 wv[8];
            #pragma unroll
            for (int r = 0; r < 8; ++r)
                wv[r] = *(const f32x4*)(wp + (size_t)(rh * 8 + r) * INF + d);
            #pragma unroll
            for (int r = 0; r < 8; ++r) {
                #pragma unroll
                for (int t = 0; t < RTM; ++t)
                    acc[rh * 8 + r][t] += wv[r].x * xv[t].x + wv[r].y * xv[t].y
                                        + wv[r].z * xv[t].z + wv[r].w * xv[t].w;
            }
        }
    }

    #pragma unroll
    for (int off = 1; off < 64; off <<= 1) {
        #pragma unroll
        for (int r = 0; r < RDIM; ++r)
            #pragma unroll
            for (int t = 0; t < RTM; ++t)
                acc[r][t] += __shfl_xor(acc[r][t], off, 64);
    }

    f32x4 kreg[4];
    #pragma unroll
    for (int i = 0; i < 4; ++i)
        kreg[i] = *(const f32x4*)&keys[lane * RDIM + i * 4];

    #pragma unroll
    for (int t = 0; t < RTM; ++t) {
        float s = 0.0f;
        #pragma unroll
        for (int i = 0; i < 4; ++i) {
            s += acc[i*4+0][t] * kreg[i].x + acc[i*4+1][t] * kreg[i].y
               + acc[i*4+2][t] * kreg[i].z + acc[i*4+3][t] * kreg[i].w;
        }
        int rank = 0;
        for (int j = 0; j < 64; ++j) {
            float sj = __shfl(s, j, 64);
            rank += (sj > s || (sj == s && j < lane)) ? 1 : 0;
        }
        float m = s;
        #pragma unroll
        for (int off = 32; off > 0; off >>= 1)
            m = fmaxf(m, __shfl_xor(m, off, 64));
        float e = (rank < TOPK) ? __expf(s - m) : 0.0f;
        float sum = e;
        #pragma unroll
        for (int off = 32; off > 0; off >>= 1)
            sum += __shfl_xor(sum, off, 64);
        gate[(t0 + t) * NEXP + lane] = e / sum;
    }
}

// ---------------- gemm0 split-K: Cp[ks] = xb[M,Kc] * Ab[N,Kc]^T (fp32 partials)
// grid = 1024 blocks (4 bx * 2 ks * 128 by), XCD-swizzled so all 8 blocks
// sharing an A-row-panel (same by) run on one XCD -> A fetched once from HBM.
__global__ void __launch_bounds__(256) gemm_sk(
    const unsigned short* __restrict__ A,   // [M][K] bf16
    const unsigned short* __restrict__ Bm,  // [N][K] bf16
    float* __restrict__ Cp,                 // [2][M][N] fp32 partials
    const int M, const int N, const int K)
{
    constexpr int BM = 128, BN = 128, BK = 32, KSPLIT = 2;
    __shared__ __align__(16) unsigned short As[BM * BK];   // 8 KB
    __shared__ __align__(16) unsigned short Bs[BN * BK];   // 8 KB

    // bijective XCD swizzle: nwg=1024, 1024%8==0
    const int flat = blockIdx.x;
    const int wg   = (flat & 7) * 128 + (flat >> 3);
    const int bx   = wg & 3;                 // N/BN = 4
    const int ks   = (wg >> 2) & (KSPLIT - 1);
    const int by   = wg >> 3;                // 0..127

    const int tid  = threadIdx.x;
    const int lane = tid & 63;
    const int wave = tid >> 6;
    const int wr = wave >> 1, wc = wave & 1;
    const int bm = by * BM;
    const int bn = bx * BN;
    const int kchunk = K / KSPLIT;           // 2048

    f32x4 acc[4][4] = {};

    const int srow = tid >> 2;
    const int scol = (tid & 3) * 8;
    const unsigned short* Ap = A  + (size_t)(bm + srow) * K + ks * kchunk + scol;
    const unsigned short* Bp = Bm + (size_t)(bn + srow) * K + ks * kchunk + scol;
    unsigned short* AsP = &As[tid * 8];
    unsigned short* BsP = &Bs[tid * 8];

    const int fm = lane & 15;
    const int fk = (lane >> 4) * 8;

    for (int k0 = 0; k0 < kchunk; k0 += BK) {
        __syncthreads();
        gld_lds16(Ap,                  AsP);
        gld_lds16(Ap + (size_t)64 * K, AsP + 64 * BK);
        gld_lds16(Bp,                  BsP);
        gld_lds16(Bp + (size_t)64 * K, BsP + 64 * BK);
        Ap += BK; Bp += BK;
        __syncthreads();

        bf16x8 af[4], bfr[4];
        #pragma unroll
        for (int i = 0; i < 4; ++i)
            af[i] = *(const bf16x8*)&As[(wr * 64 + i * 16 + fm) * BK + fk];
        #pragma unroll
        for (int j = 0; j < 4; ++j)
            bfr[j] = *(const bf16x8*)&Bs[(wc * 64 + j * 16 + fm) * BK + fk];
        #pragma unroll
        for (int i = 0; i < 4; ++i)
            #pragma unroll
            for (int j = 0; j < 4; ++j)
                acc[i][j] = __builtin_amdgcn_mfma_f32_16x16x32_bf16(af[i], bfr[j], acc[i][j], 0, 0, 0);
    }

    // C/D layout col=lane&15, row=(lane>>4)*4+reg (m89/m91-verified)
    const int row0 = (lane >> 4) * 4;
    const int col  = lane & 15;
    float* Cpo = Cp + (size_t)ks * M * N;
    #pragma unroll
    for (int i = 0; i < 4; ++i) {
        #pragma unroll
        for (int j = 0; j < 4; ++j) {
            const int nn = bn + wc * 64 + j * 16 + col;
            #pragma unroll
            for (int r = 0; r < 4; ++r) {
                const int mm = bm + wr * 64 + i * 16 + row0 + r;
                Cpo[(size_t)mm * N + nn] = acc[i][j][r];
            }
        }
    }
}

// ---------------- reduce partials + gate + cast -> Zg bf16 -------------------
__global__ void __launch_bounds__(256) reduce_gate_k(
    const float* __restrict__ Cp,     // [2][T][512] fp32
    const float* __restrict__ gate,   // [T][64]
    unsigned short* __restrict__ Zg)  // [T][512] bf16
{
    const size_t i = (size_t)blockIdx.x * 256 + threadIdx.x;   // f32x4 index
    f32x4 v = ((const f32x4*)Cp)[i];
    f32x4 w = ((const f32x4*)(Cp + (size_t)T_TOK * BOT))[i];
    const int m = (int)(i >> 7);          // 512/4 = 128 vec4 per row
    const int e = ((int)i & 127) >> 1;    // expert = (4*i % 512) / 8
    const float g = gate[(size_t)m * NEXP + e];
    ushort4 o;
    o.x = f2bf((v.x + w.x) * g);
    o.y = f2bf((v.y + w.y) * g);
    o.z = f2bf((v.z + w.z) * g);
    o.w = f2bf((v.w + w.w) * g);
    ((ushort4*)Zg)[i] = o;
}

// ---------------- m97-style bf16 B^T GEMM (final): out = Zg*Bb^T * 2.0 -------
template <int EPI>
__global__ void __launch_bounds__(256) gemm_bt(
    const unsigned short* __restrict__ A,
    const unsigned short* __restrict__ Bm,
    const float* __restrict__ gate,
    unsigned short* __restrict__ Cb,
    float* __restrict__ Cf,
    const int M, const int N, const int K)
{
    constexpr int BM = 128, BN = 128, BK = 32;
    __shared__ __align__(16) unsigned short As[BM * BK];   // 8 KB
    __shared__ __align__(16) unsigned short Bs[BN * BK];   // 8 KB

    const int tid  = threadIdx.x;
    const int lane = tid & 63;
    const int wave = tid >> 6;
    const int wr = wave >> 1, wc = wave & 1;
    const int bm = blockIdx.y * BM;
    const int bn = blockIdx.x * BN;

    f32x4 acc[4][4] = {};

    const int srow = tid >> 2;
    const int scol = (tid & 3) * 8;
    const unsigned short* Ap = A  + (size_t)(bm + srow) * K + scol;
    const unsigned short* Bp = Bm + (size_t)(bn + srow) * K + scol;
    unsigned short* AsP = &As[tid * 8];
    unsigned short* BsP = &Bs[tid * 8];

    const int fm = lane & 15;
    const int fk = (lane >> 4) * 8;

    for (int k0 = 0; k0 < K; k0 += BK) {
        __syncthreads();
        gld_lds16(Ap,                  AsP);
        gld_lds16(Ap + (size_t)64 * K, AsP + 64 * BK);
        gld_lds16(Bp,                  BsP);
        gld_lds16(Bp + (size_t)64 * K, BsP + 64 * BK);
        Ap += BK; Bp += BK;
        __syncthreads();

        bf16x8 af[4], bfr[4];
        #pragma unroll
        for (int i = 0; i < 4; ++i)
            af[i] = *(const bf16x8*)&As[(wr * 64 + i * 16 + fm) * BK + fk];
        #pragma unroll
        for (int j = 0; j < 4; ++j)
            bfr[j] = *(const bf16x8*)&Bs[(wc * 64 + j * 16 + fm) * BK + fk];
        #pragma unroll
        for (int i = 0; i < 4; ++i)
            #pragma unroll
            for (int j = 0; j < 4; ++j)
                acc[i][j] = __builtin_amdgcn_mfma_f32_16x16x32_bf16(af[i], bfr[j], acc[i][j], 0, 0, 0);
    }

    const int row0 = (lane >> 4) * 4;
    const int col  = lane & 15;
    #pragma unroll
    for (int i = 0; i < 4; ++i) {
        #pragma unroll
        for (int j = 0; j < 4; ++j) {
            const int nn = bn + wc * 64 + j * 16 + col;
            #pragma unroll
            for (int r = 0; r < 4; ++r) {
                const int mm = bm + wr * 64 + i * 16 + row0 + r;
                if (EPI == 0) {
                    float g = gate[(size_t)mm * NEXP + (nn >> 3)];
                    Cb[(size_t)mm * N + nn] = f2bf(acc[i][j][r] * g);
                } else {
                    Cf[(size_t)mm * N + nn] = acc[i][j][r] * 2.0f;
                }
            }
        }
    }
}

extern "C" void kernel_launch(void* const* d_in, const int* in_sizes, int n_in,
                              void* d_out, int out_size, void* d_ws, size_t ws_size,
                              hipStream_t stream) {
    const float* x    = (const float*)d_in[0];
    const float* A_w  = (const float*)d_in[1];
    const float* B_w  = (const float*)d_in[2];
    const float* Wq   = (const float*)d_in[3];
    const float* keys = (const float*)d_in[4];
    float* out = (float*)d_out;

    char* ws = (char*)d_ws;
    unsigned short* xb = (unsigned short*)(ws);                       // 134217728 B
    unsigned short* Ab = (unsigned short*)(ws + 134217728);           //   4194304 B
    unsigned short* Bb = (unsigned short*)(ws + 138412032);           //   4194304 B
    float*        gate = (float*)        (ws + 142606336);            //   4194304 B
    unsigned short* Zg = (unsigned short*)(ws + 146800640);           //  16777216 B
    // total ws use: 163,577,856 B

    // split-K partials live in the (still-dead) out buffer: 2*33.5MB <= 268MB
    float* Cp = out;

    cast_w<<<dim3(4096), dim3(256), 0, stream>>>(A_w, B_w, Ab, Bb);
    router_kernel<<<dim3(T_TOK / (RTM * 4)), dim3(256), 0, stream>>>(x, Wq, keys, xb, gate);
    gemm_sk<<<dim3(1024), dim3(256), 0, stream>>>(xb, Ab, Cp, T_TOK, BOT, INF);
    reduce_gate_k<<<dim3(T_TOK * BOT / 4 / 256), dim3(256), 0, stream>>>(Cp, gate, Zg);
    gemm_bt<1><<<dim3(OUTF / 128, T_TOK / 128), dim3(256), 0, stream>>>(
        Zg, Bb, nullptr, nullptr, out, T_TOK, OUTF, BOT);
}